// Round 7
// baseline (447.481 us; speedup 1.0000x reference)
//
#include <hip/hip_runtime.h>

#define DIM 256
#define KNN 16
#define SLOPE 0.2f

typedef unsigned short u16;
typedef __attribute__((ext_vector_type(8))) unsigned short u16x8;
typedef __attribute__((ext_vector_type(4))) unsigned short u16x4;
typedef __attribute__((ext_vector_type(8))) short s16x8;
typedef __attribute__((ext_vector_type(4))) float f32x4;

__device__ __forceinline__ float leaky(float x) { return x >= 0.f ? x : SLOPE * x; }
// f32 -> bf16 (RNE) as raw u16; inputs are finite (no NaN handling needed)
__device__ __forceinline__ u16 f2bu(float f) {
    unsigned int u = __float_as_uint(f);
    u = (u + 0x7FFFu + ((u >> 16) & 1u)) >> 16;
    return (u16)u;
}
__device__ __forceinline__ float bu2f(u16 h) {
    return __uint_as_float(((unsigned int)h) << 16);
}

// ---------------------------------------------------------------------------
// Prep: weights -> bf16 in MFMA fragment order so GEMM kernels load B frags
// directly from global (L2-resident broadcast): no LDS staging for B.
// Fragment (ct, ks): lane l holds w[k = ks*32 + (l>>4)*8 + j][col = ct*16 + (l&15)]
// at wT[((ct*8+ks)*64 + l)*8 + j].
// wT1: ct 0..15 = w_res cols, ct 16..19 = w_init cols. wT3: w_fin cols.
__global__ __launch_bounds__(256) void k_prep(
    const float* __restrict__ w_res, const float* __restrict__ w_init,
    const float* __restrict__ w_fin, u16* __restrict__ wT1, u16* __restrict__ wT3)
{
    const int t = blockIdx.x * 256 + threadIdx.x;
    if (t < 20 * 8 * 64) {               // wT1: 10240 entries x 8 u16
        const int lane = t & 63, frag = t >> 6;
        const int ks = frag & 7, ct = frag >> 3;
        const int col = ct * 16 + (lane & 15);
        const int k0 = ks * 32 + (lane >> 4) * 8;
        u16x8 p;
        #pragma unroll
        for (int j = 0; j < 8; ++j) {
            float v = (col < 256) ? w_res[(size_t)(k0 + j) * 256 + col]
                                  : w_init[(size_t)(k0 + j) * 64 + (col - 256)];
            p[j] = f2bu(v);
        }
        *(u16x8*)(wT1 + (size_t)t * 8) = p;
    } else if (t < 20 * 8 * 64 + 16 * 8 * 64) {  // wT3: 8192 entries x 8 u16
        const int u = t - 20 * 8 * 64;
        const int lane = u & 63, frag = u >> 6;
        const int ks = frag & 7, ct = frag >> 3;
        const int col = ct * 16 + (lane & 15);
        const int k0 = ks * 32 + (lane >> 4) * 8;
        u16x8 p;
        #pragma unroll
        for (int j = 0; j < 8; ++j)
            p[j] = f2bu(w_fin[(size_t)(k0 + j) * 256 + col]);
        *(u16x8*)(wT3 + (size_t)u * 8) = p;
    }
}

#define APAD 264  // 256+8 bf16 elems; 528B row stride -> 16B aligned

// ---------------------------------------------------------------------------
// GEMM1 (round-1 proven): rows=64/block, cols=320 (0..255 -> resid f32 in
// d_out, 256..319 -> a1 bf16), K=256. A full-K in LDS (1 barrier); B frags
// direct from global wT1 (fragment order, L2-resident).
__global__ __launch_bounds__(256) void k_gemm1(
    const float* __restrict__ in, const u16* __restrict__ wT1,
    const float* __restrict__ b_res, const float* __restrict__ b_init,
    float* __restrict__ resid, u16* __restrict__ a1, int N)
{
    __shared__ u16 A_s[64 * APAD];   // 33792 B
    const int t = threadIdx.x;
    const int base = blockIdx.x * 64;

    {
        const int row = t >> 2, seg = t & 3;
        const int grow = min(base + row, N - 1);
        const float* src = in + (size_t)grow * DIM + seg * 64;
        u16* dst = &A_s[row * APAD + seg * 64];
        #pragma unroll
        for (int j = 0; j < 8; ++j) {
            float4 f0 = *(const float4*)(src + j * 8);
            float4 f1 = *(const float4*)(src + j * 8 + 4);
            u16x8 p;
            p[0] = f2bu(f0.x); p[1] = f2bu(f0.y); p[2] = f2bu(f0.z); p[3] = f2bu(f0.w);
            p[4] = f2bu(f1.x); p[5] = f2bu(f1.y); p[6] = f2bu(f1.z); p[7] = f2bu(f1.w);
            *(u16x8*)(dst + j * 8) = p;
        }
    }
    __syncthreads();  // the only barrier

    f32x4 acc[4][5];
    #pragma unroll
    for (int i = 0; i < 4; ++i)
        #pragma unroll
        for (int j = 0; j < 5; ++j)
            acc[i][j] = (f32x4){0.f, 0.f, 0.f, 0.f};

    const int w = t >> 6, lane = t & 63;
    const int llow = lane & 15, lhi = lane >> 4;

    for (int ks = 0; ks < 8; ++ks) {
        s16x8 bfrag[5];
        #pragma unroll
        for (int ci = 0; ci < 5; ++ci) {
            const int ct = w * 5 + ci;
            bfrag[ci] = *(const s16x8*)(wT1 + ((size_t)(ct * 8 + ks) * 64 + lane) * 8);
        }
        s16x8 afrag[4];
        #pragma unroll
        for (int rt = 0; rt < 4; ++rt)
            afrag[rt] = *(const s16x8*)(&A_s[(rt * 16 + llow) * APAD + ks * 32 + lhi * 8]);
        #pragma unroll
        for (int ci = 0; ci < 5; ++ci)
            #pragma unroll
            for (int rt = 0; rt < 4; ++rt)
                acc[rt][ci] = __builtin_amdgcn_mfma_f32_16x16x32_bf16(
                    afrag[rt], bfrag[ci], acc[rt][ci], 0, 0, 0);
    }

    #pragma unroll
    for (int ci = 0; ci < 5; ++ci) {
        const int ct = w * 5 + ci;
        const int col = ct * 16 + llow;
        if (col < 256) {
            const float bias = b_res[col];
            #pragma unroll
            for (int rt = 0; rt < 4; ++rt)
                #pragma unroll
                for (int r = 0; r < 4; ++r) {
                    int row = base + rt * 16 + lhi * 4 + r;
                    if (row < N)
                        resid[(size_t)row * DIM + col] = leaky(acc[rt][ci][r] + bias);
                }
        } else {
            const int c2 = col - 256;
            const float bias = b_init[c2];
            #pragma unroll
            for (int rt = 0; rt < 4; ++rt)
                #pragma unroll
                for (int r = 0; r < 4; ++r) {
                    int row = base + rt * 16 + lhi * 4 + r;
                    if (row < N)
                        a1[(size_t)row * 64 + c2] = f2bu(leaky(acc[rt][ci][r] + bias));
                }
        }
    }
}

// ---------------------------------------------------------------------------
// LFA1: 16 points/block. [round-0/1 proven version, a2 row layout [N][128]]
__global__ __launch_bounds__(256) void k_lfa1(
    const float* __restrict__ geom, const int* __restrict__ idx,
    const float* __restrict__ w_g1, const float* __restrict__ b_g1,
    const u16* __restrict__ a1, u16* __restrict__ a2, int N)
{
    __shared__ float geom_s[16 * KNN * 4];  // 4 KB
    __shared__ int idx_s[16 * KNN];         // 1 KB
    const int t = threadIdx.x;
    const int base = blockIdx.x * 16;

    {
        size_t off = (size_t)base * 64 + t * 4;
        size_t mx = (size_t)N * 64 - 4;
        if (off > mx) off = mx;
        *(float4*)&geom_s[t * 4] = *(const float4*)(geom + off);
        int io = base * KNN + t;
        if (t < 256) idx_s[t] = idx[min(io, N * KNN - 1)];
    }
    __syncthreads();

    const int pt = t >> 4, s = t & 15;
    const int n = base + pt;

    float wr[4][4], bb[4];
    #pragma unroll
    for (int r = 0; r < 4; ++r)
        #pragma unroll
        for (int j = 0; j < 4; ++j)
            wr[r][j] = w_g1[r * 64 + s * 4 + j];
    #pragma unroll
    for (int j = 0; j < 4; ++j) bb[j] = b_g1[s * 4 + j];

    float accM[4] = {0.f, 0.f, 0.f, 0.f};
    const float4* g4 = (const float4*)&geom_s[pt * 64];
    #pragma unroll
    for (int k = 0; k < KNN; ++k) {
        float4 g = g4[k];
        #pragma unroll
        for (int j = 0; j < 4; ++j)
            accM[j] += leaky(g.x * wr[0][j] + g.y * wr[1][j] + g.z * wr[2][j] + g.w * wr[3][j] + bb[j]);
    }

    // gather: 16 lanes per pt cover the whole 128B a1 row contiguously (coalesced)
    float accG[4] = {0.f, 0.f, 0.f, 0.f};
    #pragma unroll
    for (int k = 0; k < KNN; ++k) {
        u16x4 u = *(const u16x4*)(a1 + (size_t)idx_s[pt * KNN + k] * 64 + s * 4);
        #pragma unroll
        for (int j = 0; j < 4; ++j) accG[j] += bu2f(u[j]);
    }

    if (n < N) {
        u16x4 pm, pg;
        #pragma unroll
        for (int j = 0; j < 4; ++j) {
            pm[j] = f2bu(accM[j] * 0.0625f);
            pg[j] = f2bu(accG[j] * 0.0625f);
        }
        *(u16x4*)(a2 + (size_t)n * 128 + s * 4) = pm;
        *(u16x4*)(a2 + (size_t)n * 128 + 64 + s * 4) = pg;
    }
}

// ---------------------------------------------------------------------------
// LFA2 + final GEMM fused, register-resident decomposition: 64 pts/block,
// thread = (pt = t>>2, q = t&3). Phase A: gather a2 rows (coalesced 64B/pt
// per step, idx read per-thread int4 = 4-lane broadcast) -> a3 cols 128..255.
// Phase B: geom MLP with the point's 16 float4 geom rows held in REGISTERS
// (loaded once, 4-lane broadcast; zero LDS reads in the k-loop) -> cols
// q*32..q*32+31. Then one barrier, MFMA vs wT3, epilogue + resid RMW.
// LDS = a3_s only (33792 B) -> 4 blocks/CU; __launch_bounds__(256,4) caps
// VGPR at 128 so 16 waves/CU actually reside (vs round-1's 8).
__global__ __launch_bounds__(256, 4) void k_lfa2_fin(
    const float* __restrict__ geom, const int* __restrict__ idx,
    const float* __restrict__ w_g2, const float* __restrict__ b_g2,
    const u16* __restrict__ a2, const u16* __restrict__ wT3,
    const float* __restrict__ b_fin, float* __restrict__ out, int N)
{
    __shared__ u16 a3_s[64 * APAD];  // 33792 B
    const int t = threadIdx.x;
    const int base = blockIdx.x * 64;
    const int pt = t >> 2, q = t & 3;
    const int n = min(base + pt, N - 1);  // clamped rows >= N are never stored

    // ---- phase A: gather -> a3 cols 128..255 ----
    // step j: lane q reads u16x8 at row elem offset j*32 + q*8 -> the 4 lanes
    // of a pt cover 64 contiguous bytes per step (1 transaction each).
    {
        int4 i0 = *(const int4*)(idx + (size_t)n * KNN);
        int4 i1 = *(const int4*)(idx + (size_t)n * KNN + 4);
        int4 i2 = *(const int4*)(idx + (size_t)n * KNN + 8);
        int4 i3 = *(const int4*)(idx + (size_t)n * KNN + 12);
        const int ind[16] = {i0.x, i0.y, i0.z, i0.w, i1.x, i1.y, i1.z, i1.w,
                             i2.x, i2.y, i2.z, i2.w, i3.x, i3.y, i3.z, i3.w};
        float acc[4][8];
        #pragma unroll
        for (int j = 0; j < 4; ++j)
            #pragma unroll
            for (int i = 0; i < 8; ++i) acc[j][i] = 0.f;
        for (int k = 0; k < KNN; ++k) {
            const u16* row = a2 + (size_t)ind[k] * 128;
            u16x8 u[4];
            #pragma unroll
            for (int j = 0; j < 4; ++j)
                u[j] = *(const u16x8*)(row + j * 32 + q * 8);
            #pragma unroll
            for (int j = 0; j < 4; ++j)
                #pragma unroll
                for (int i = 0; i < 8; ++i) acc[j][i] += bu2f(u[j][i]);
        }
        #pragma unroll
        for (int j = 0; j < 4; ++j) {
            u16x8 p;
            #pragma unroll
            for (int i = 0; i < 8; ++i) p[i] = f2bu(acc[j][i] * 0.0625f);
            *(u16x8*)(&a3_s[pt * APAD + 128 + j * 32 + q * 8]) = p;
        }
    }

    // ---- phase B: geom MLP from registers -> a3 cols q*32 .. q*32+31 ----
    {
        float4 g[KNN];
        const float4* gp = (const float4*)(geom + (size_t)n * 64);
        #pragma unroll
        for (int k = 0; k < KNN; ++k) g[k] = gp[k];  // 4-lane broadcast, read once
        #pragma unroll
        for (int v = 0; v < 4; ++v) {
            u16x8 p;
            #pragma unroll
            for (int j = 0; j < 8; ++j) {
                const int c = q * 32 + v * 8 + j;
                const float w0 = w_g2[c], w1 = w_g2[128 + c],
                            w2 = w_g2[256 + c], w3 = w_g2[384 + c];
                const float bb = b_g2[c];
                float s = 0.f;
                #pragma unroll
                for (int k = 0; k < KNN; ++k)
                    s += leaky(g[k].x * w0 + g[k].y * w1 + g[k].z * w2 + g[k].w * w3 + bb);
                p[j] = f2bu(s * 0.0625f);
            }
            *(u16x8*)(&a3_s[pt * APAD + q * 32 + v * 8]) = p;
        }
    }
    __syncthreads();  // a3_s complete; MFMA loop below is barrier-free

    f32x4 acc[4][4];
    #pragma unroll
    for (int i = 0; i < 4; ++i)
        #pragma unroll
        for (int j = 0; j < 4; ++j)
            acc[i][j] = (f32x4){0.f, 0.f, 0.f, 0.f};

    const int w = t >> 6, lane = t & 63;
    const int llow = lane & 15, lhi = lane >> 4;

    for (int ks = 0; ks < 8; ++ks) {
        s16x8 bfrag[4];
        #pragma unroll
        for (int ci = 0; ci < 4; ++ci) {
            const int ct = w * 4 + ci;
            bfrag[ci] = *(const s16x8*)(wT3 + ((size_t)(ct * 8 + ks) * 64 + lane) * 8);
        }
        s16x8 afrag[4];
        #pragma unroll
        for (int rt = 0; rt < 4; ++rt)
            afrag[rt] = *(const s16x8*)(&a3_s[(rt * 16 + llow) * APAD + ks * 32 + lhi * 8]);
        #pragma unroll
        for (int ci = 0; ci < 4; ++ci)
            #pragma unroll
            for (int rt = 0; rt < 4; ++rt)
                acc[rt][ci] = __builtin_amdgcn_mfma_f32_16x16x32_bf16(
                    afrag[rt], bfrag[ci], acc[rt][ci], 0, 0, 0);
    }

    #pragma unroll
    for (int ci = 0; ci < 4; ++ci) {
        const int ct = w * 4 + ci;
        const int col = ct * 16 + llow;
        const float bias = b_fin[col];
        #pragma unroll
        for (int rt = 0; rt < 4; ++rt)
            #pragma unroll
            for (int r = 0; r < 4; ++r) {
                int row = base + rt * 16 + lhi * 4 + r;
                if (row < N) {
                    size_t o = (size_t)row * DIM + col;
                    out[o] = leaky(acc[rt][ci][r] + bias) + out[o];
                }
            }
    }
}

// ---------------------------------------------------------------------------
extern "C" void kernel_launch(void* const* d_in, const int* in_sizes, int n_in,
                              void* d_out, int out_size, void* d_ws, size_t ws_size,
                              hipStream_t stream) {
    const float* in    = (const float*)d_in[0];
    const float* geom  = (const float*)d_in[1];
    const int*   idx   = (const int*)d_in[2];
    const float* w_res = (const float*)d_in[3];
    const float* b_res = (const float*)d_in[4];
    const float* w_init= (const float*)d_in[5];
    const float* b_init= (const float*)d_in[6];
    const float* w_g1  = (const float*)d_in[7];
    const float* b_g1  = (const float*)d_in[8];
    const float* w_g2  = (const float*)d_in[9];
    const float* b_g2  = (const float*)d_in[10];
    const float* w_fin = (const float*)d_in[11];
    const float* b_fin = (const float*)d_in[12];
    float* out = (float*)d_out;

    const int N = in_sizes[0] / DIM;  // 50000

    // ws: a1 N*64 bf16 | a2 N*128 bf16 | wT1 320*256 bf16 | wT3 256*256 bf16
    char* ws = (char*)d_ws;
    u16* a1  = (u16*)ws;
    u16* a2  = a1 + (size_t)N * 64;
    u16* wT1 = a2 + (size_t)N * 128;
    u16* wT3 = wT1 + 320 * 256;

    k_prep<<<72, 256, 0, stream>>>(w_res, w_init, w_fin, wT1, wT3);
    k_gemm1<<<(N + 63) / 64, 256, 0, stream>>>(in, wT1, b_res, b_init, out, a1, N);
    k_lfa1<<<(N + 15) / 16, 256, 0, stream>>>(geom, idx, w_g1, b_g1, a1, a2, N);
    k_lfa2_fin<<<(N + 63) / 64, 256, 0, stream>>>(geom, idx, w_g2, b_g2, a2, wT3, b_fin, out, N);
}

// Round 8
// 279.698 us; speedup vs baseline: 1.5999x; 1.5999x over previous
//
#include <hip/hip_runtime.h>

#define DIM 256
#define KNN 16
#define SLOPE 0.2f

typedef unsigned short u16;
typedef __attribute__((ext_vector_type(8))) unsigned short u16x8;
typedef __attribute__((ext_vector_type(4))) unsigned short u16x4;
typedef __attribute__((ext_vector_type(8))) short s16x8;
typedef __attribute__((ext_vector_type(4))) float f32x4;

__device__ __forceinline__ float leaky(float x) { return x >= 0.f ? x : SLOPE * x; }
// f32 -> bf16 (RNE) as raw u16; inputs are finite (no NaN handling needed)
__device__ __forceinline__ u16 f2bu(float f) {
    unsigned int u = __float_as_uint(f);
    u = (u + 0x7FFFu + ((u >> 16) & 1u)) >> 16;
    return (u16)u;
}
__device__ __forceinline__ float bu2f(u16 h) {
    return __uint_as_float(((unsigned int)h) << 16);
}

// ---------------------------------------------------------------------------
// Prep: weights -> bf16 in MFMA fragment order so GEMM kernels load B frags
// directly from global (L2-resident broadcast): no LDS staging for B.
// Fragment (ct, ks): lane l holds w[k = ks*32 + (l>>4)*8 + j][col = ct*16 + (l&15)]
// at wT[((ct*8+ks)*64 + l)*8 + j].
// wT1: ct 0..15 = w_res cols, ct 16..19 = w_init cols. wT3: w_fin cols.
__global__ __launch_bounds__(256) void k_prep(
    const float* __restrict__ w_res, const float* __restrict__ w_init,
    const float* __restrict__ w_fin, u16* __restrict__ wT1, u16* __restrict__ wT3)
{
    const int t = blockIdx.x * 256 + threadIdx.x;
    if (t < 20 * 8 * 64) {               // wT1: 10240 entries x 8 u16
        const int lane = t & 63, frag = t >> 6;
        const int ks = frag & 7, ct = frag >> 3;
        const int col = ct * 16 + (lane & 15);
        const int k0 = ks * 32 + (lane >> 4) * 8;
        u16x8 p;
        #pragma unroll
        for (int j = 0; j < 8; ++j) {
            float v = (col < 256) ? w_res[(size_t)(k0 + j) * 256 + col]
                                  : w_init[(size_t)(k0 + j) * 64 + (col - 256)];
            p[j] = f2bu(v);
        }
        *(u16x8*)(wT1 + (size_t)t * 8) = p;
    } else if (t < 20 * 8 * 64 + 16 * 8 * 64) {  // wT3: 8192 entries x 8 u16
        const int u = t - 20 * 8 * 64;
        const int lane = u & 63, frag = u >> 6;
        const int ks = frag & 7, ct = frag >> 3;
        const int col = ct * 16 + (lane & 15);
        const int k0 = ks * 32 + (lane >> 4) * 8;
        u16x8 p;
        #pragma unroll
        for (int j = 0; j < 8; ++j)
            p[j] = f2bu(w_fin[(size_t)(k0 + j) * 256 + col]);
        *(u16x8*)(wT3 + (size_t)u * 8) = p;
    }
}

#define APAD 264  // 256+8 bf16 elems; 528B row stride -> 16B aligned

// ---------------------------------------------------------------------------
// GEMM1 epilogue helper: one 16-col tile (4 row-tiles x 4 regs) of C.
__device__ __forceinline__ void epi_gemm1(
    int base, int N, int ct, int llow, int lhi, const f32x4* acc4,
    const float* __restrict__ b_res, const float* __restrict__ b_init,
    float* __restrict__ resid, u16* __restrict__ a1)
{
    const int col = ct * 16 + llow;
    if (col < 256) {
        const float bias = b_res[col];
        #pragma unroll
        for (int rt = 0; rt < 4; ++rt)
            #pragma unroll
            for (int r = 0; r < 4; ++r) {
                int row = base + rt * 16 + lhi * 4 + r;
                if (row < N)
                    resid[(size_t)row * DIM + col] = leaky(acc4[rt][r] + bias);
            }
    } else {
        const int c2 = col - 256;
        const float bias = b_init[c2];
        #pragma unroll
        for (int rt = 0; rt < 4; ++rt)
            #pragma unroll
            for (int r = 0; r < 4; ++r) {
                int row = base + rt * 16 + lhi * 4 + r;
                if (row < N)
                    a1[(size_t)row * 64 + c2] = f2bu(leaky(acc4[rt][r] + bias));
            }
    }
}

// GEMM1: rows=64/block, cols=320 (0..255 -> resid f32 in d_out, 256..319 ->
// a1 bf16), K=256. A full-K in LDS (1 barrier); B frags direct from global
// wT1. Column tiles split into two passes (3+2) to cut acc VGPR 80->48;
// __launch_bounds__(256,4) caps VGPR at 128 -> 4 blocks/CU co-resident
// (LDS 4x33792 = 132KB <= 160KB). A_s re-read in pass 1 is free (LDS).
__global__ __launch_bounds__(256, 4) void k_gemm1(
    const float* __restrict__ in, const u16* __restrict__ wT1,
    const float* __restrict__ b_res, const float* __restrict__ b_init,
    float* __restrict__ resid, u16* __restrict__ a1, int N)
{
    __shared__ u16 A_s[64 * APAD];   // 33792 B
    const int t = threadIdx.x;
    const int base = blockIdx.x * 64;

    {
        const int row = t >> 2, seg = t & 3;
        const int grow = min(base + row, N - 1);
        const float* src = in + (size_t)grow * DIM + seg * 64;
        u16* dst = &A_s[row * APAD + seg * 64];
        #pragma unroll
        for (int j = 0; j < 8; ++j) {
            float4 f0 = *(const float4*)(src + j * 8);
            float4 f1 = *(const float4*)(src + j * 8 + 4);
            u16x8 p;
            p[0] = f2bu(f0.x); p[1] = f2bu(f0.y); p[2] = f2bu(f0.z); p[3] = f2bu(f0.w);
            p[4] = f2bu(f1.x); p[5] = f2bu(f1.y); p[6] = f2bu(f1.z); p[7] = f2bu(f1.w);
            *(u16x8*)(dst + j * 8) = p;
        }
    }
    __syncthreads();  // the only barrier

    const int w = t >> 6, lane = t & 63;
    const int llow = lane & 15, lhi = lane >> 4;

    // ---- pass 0: local col tiles 0..2 ----
    {
        f32x4 acc[3][4];
        #pragma unroll
        for (int i = 0; i < 3; ++i)
            #pragma unroll
            for (int j = 0; j < 4; ++j)
                acc[i][j] = (f32x4){0.f, 0.f, 0.f, 0.f};
        for (int ks = 0; ks < 8; ++ks) {
            s16x8 bfrag[3];
            #pragma unroll
            for (int ci = 0; ci < 3; ++ci) {
                const int ct = w * 5 + ci;
                bfrag[ci] = *(const s16x8*)(wT1 + ((size_t)(ct * 8 + ks) * 64 + lane) * 8);
            }
            s16x8 afrag[4];
            #pragma unroll
            for (int rt = 0; rt < 4; ++rt)
                afrag[rt] = *(const s16x8*)(&A_s[(rt * 16 + llow) * APAD + ks * 32 + lhi * 8]);
            #pragma unroll
            for (int ci = 0; ci < 3; ++ci)
                #pragma unroll
                for (int rt = 0; rt < 4; ++rt)
                    acc[ci][rt] = __builtin_amdgcn_mfma_f32_16x16x32_bf16(
                        afrag[rt], bfrag[ci], acc[ci][rt], 0, 0, 0);
        }
        #pragma unroll
        for (int ci = 0; ci < 3; ++ci)
            epi_gemm1(base, N, w * 5 + ci, llow, lhi, acc[ci], b_res, b_init, resid, a1);
    }
    // ---- pass 1: local col tiles 3..4 ----
    {
        f32x4 acc[2][4];
        #pragma unroll
        for (int i = 0; i < 2; ++i)
            #pragma unroll
            for (int j = 0; j < 4; ++j)
                acc[i][j] = (f32x4){0.f, 0.f, 0.f, 0.f};
        for (int ks = 0; ks < 8; ++ks) {
            s16x8 bfrag[2];
            #pragma unroll
            for (int ci = 0; ci < 2; ++ci) {
                const int ct = w * 5 + 3 + ci;
                bfrag[ci] = *(const s16x8*)(wT1 + ((size_t)(ct * 8 + ks) * 64 + lane) * 8);
            }
            s16x8 afrag[4];
            #pragma unroll
            for (int rt = 0; rt < 4; ++rt)
                afrag[rt] = *(const s16x8*)(&A_s[(rt * 16 + llow) * APAD + ks * 32 + lhi * 8]);
            #pragma unroll
            for (int ci = 0; ci < 2; ++ci)
                #pragma unroll
                for (int rt = 0; rt < 4; ++rt)
                    acc[ci][rt] = __builtin_amdgcn_mfma_f32_16x16x32_bf16(
                        afrag[rt], bfrag[ci], acc[ci][rt], 0, 0, 0);
        }
        #pragma unroll
        for (int ci = 0; ci < 2; ++ci)
            epi_gemm1(base, N, w * 5 + 3 + ci, llow, lhi, acc[ci], b_res, b_init, resid, a1);
    }
}

// ---------------------------------------------------------------------------
// LFA1, wide-load version: 32 points/block, 8 lanes/pt (s = t&7), each lane
// owns 8 cols. Gather loads are u16x8 (16B/lane; 8 lanes cover the 128B a1
// row contiguously) -- half the load instructions of the u16x4 version for
// identical bytes -- with k unrolled x2 (2 rows in flight). MLP weights in
// registers; geom/idx staged in LDS (10KB). All arrays statically indexed.
__global__ __launch_bounds__(256) void k_lfa1(
    const float* __restrict__ geom, const int* __restrict__ idx,
    const float* __restrict__ w_g1, const float* __restrict__ b_g1,
    const u16* __restrict__ a1, u16* __restrict__ a2, int N)
{
    __shared__ float geom_s[32 * KNN * 4];  // 8 KB
    __shared__ int idx_s[32 * KNN];         // 2 KB
    const int t = threadIdx.x;
    const int base = blockIdx.x * 32;

    {
        size_t mx = (size_t)N * 64 - 4;
        size_t off0 = (size_t)base * 64 + t * 4;
        size_t off1 = off0 + 1024;
        if (off0 > mx) off0 = mx;
        if (off1 > mx) off1 = mx;
        *(float4*)&geom_s[t * 4] = *(const float4*)(geom + off0);
        *(float4*)&geom_s[1024 + t * 4] = *(const float4*)(geom + off1);
        const int imx = N * KNN - 1;
        idx_s[t] = idx[min(base * KNN + t, imx)];
        idx_s[t + 256] = idx[min(base * KNN + 256 + t, imx)];
    }
    __syncthreads();

    const int pt = t >> 3, s = t & 7;
    const int n = base + pt;

    // geom MLP: cols s*8..s*8+7, weights in regs
    float wr[4][8], bb[8];
    #pragma unroll
    for (int r = 0; r < 4; ++r)
        #pragma unroll
        for (int j = 0; j < 8; ++j)
            wr[r][j] = w_g1[r * 64 + s * 8 + j];
    #pragma unroll
    for (int j = 0; j < 8; ++j) bb[j] = b_g1[s * 8 + j];

    float accM[8];
    #pragma unroll
    for (int j = 0; j < 8; ++j) accM[j] = 0.f;
    const float4* g4 = (const float4*)&geom_s[pt * 64];
    #pragma unroll
    for (int k = 0; k < KNN; ++k) {
        float4 g = g4[k];
        #pragma unroll
        for (int j = 0; j < 8; ++j)
            accM[j] += leaky(g.x * wr[0][j] + g.y * wr[1][j] + g.z * wr[2][j] + g.w * wr[3][j] + bb[j]);
    }

    // gather: 8 lanes x u16x8 cover the 128B a1 row; 2 rows in flight
    float accG[8];
    #pragma unroll
    for (int j = 0; j < 8; ++j) accG[j] = 0.f;
    #pragma unroll
    for (int k = 0; k < KNN; k += 2) {
        u16x8 u0 = *(const u16x8*)(a1 + (size_t)idx_s[pt * KNN + k] * 64 + s * 8);
        u16x8 u1 = *(const u16x8*)(a1 + (size_t)idx_s[pt * KNN + k + 1] * 64 + s * 8);
        #pragma unroll
        for (int j = 0; j < 8; ++j) accG[j] += bu2f(u0[j]) + bu2f(u1[j]);
    }

    if (n < N) {
        u16x8 pm, pg;
        #pragma unroll
        for (int j = 0; j < 8; ++j) {
            pm[j] = f2bu(accM[j] * 0.0625f);
            pg[j] = f2bu(accG[j] * 0.0625f);
        }
        *(u16x8*)(a2 + (size_t)n * 128 + s * 8) = pm;
        *(u16x8*)(a2 + (size_t)n * 128 + 64 + s * 8) = pg;
    }
}

// ---------------------------------------------------------------------------
// LFA2 + final GEMM fused [FROZEN: round-6 best, 111us]: 64 points/block.
// Build a3[64][256] bf16 in LDS (cols 0..127 geom-MLP, 128..255 a2-gather,
// coalesced 64B/pt/step lane map), MFMA vs wT3 (B frags from global),
// epilogue leaky(+b_fin) + resid RMW on out. 2 blocks/CU operating point
// protects the a2 gather's L2 reuse (rounds 2/3/7 falsified alternatives).
__global__ __launch_bounds__(256) void k_lfa2_fin(
    const float* __restrict__ geom, const int* __restrict__ idx,
    const float* __restrict__ w_g2, const float* __restrict__ b_g2,
    const u16* __restrict__ a2, const u16* __restrict__ wT3,
    const float* __restrict__ b_fin, float* __restrict__ out, int N)
{
    __shared__ u16 a3_s[64 * APAD];         // 33792 B
    __shared__ float geom_s[64 * KNN * 4];  // 16384 B
    __shared__ int idx_s[64 * KNN];         // 4096 B
    const int t = threadIdx.x;
    const int base = blockIdx.x * 64;

    // stage geom + idx (clamped; clamped rows are >= N and never stored)
    {
        size_t mx = (size_t)N * 64 - 4;
        #pragma unroll
        for (int j = 0; j < 4; ++j) {
            size_t off = (size_t)base * 64 + t * 4 + j * 1024;
            if (off > mx) off = mx;
            *(float4*)&geom_s[t * 4 + j * 1024] = *(const float4*)(geom + off);
        }
        int imx = N * KNN - 1;
        #pragma unroll
        for (int j = 0; j < 4; ++j) {
            int off = base * KNN + t + j * 256;
            idx_s[t + j * 256] = idx[min(off, imx)];
        }
    }
    __syncthreads();

    // geom MLP -> a3 cols 0..127. thread = (c = t&127, h = t>>7 -> 32 pts)
    {
        const int c = t & 127, h = t >> 7;
        const float w0 = w_g2[c], w1 = w_g2[128 + c], w2 = w_g2[256 + c],
                    w3 = w_g2[384 + c], bb = b_g2[c];
        for (int p = 0; p < 32; ++p) {
            const int pt = h * 32 + p;
            float acc = 0.f;
            const float4* g4 = (const float4*)&geom_s[pt * 64];
            #pragma unroll
            for (int k = 0; k < KNN; ++k) {
                float4 g = g4[k];
                acc += leaky(g.x * w0 + g.y * w1 + g.z * w2 + g.w * w3 + bb);
            }
            a3_s[pt * APAD + c] = f2bu(acc * 0.0625f);
        }
    }
    // gather -> a3 cols 128..255. thread = (pt = t>>2, q = t&3).
    // step j: lane q reads u16x8 at row elem offset j*32 + q*8 -> the 4 lanes
    // of a pt cover 64 contiguous bytes per step (coalesced into 1 transaction).
    {
        const int pt = t >> 2, q = t & 3;
        float acc[4][8];
        #pragma unroll
        for (int j = 0; j < 4; ++j)
            #pragma unroll
            for (int i = 0; i < 8; ++i) acc[j][i] = 0.f;
        for (int k = 0; k < KNN; ++k) {
            const u16* row = a2 + (size_t)idx_s[pt * KNN + k] * 128;
            u16x8 u[4];
            #pragma unroll
            for (int j = 0; j < 4; ++j)
                u[j] = *(const u16x8*)(row + j * 32 + q * 8);
            #pragma unroll
            for (int j = 0; j < 4; ++j)
                #pragma unroll
                for (int i = 0; i < 8; ++i) acc[j][i] += bu2f(u[j][i]);
        }
        #pragma unroll
        for (int j = 0; j < 4; ++j) {
            u16x8 p;
            #pragma unroll
            for (int i = 0; i < 8; ++i) p[i] = f2bu(acc[j][i] * 0.0625f);
            *(u16x8*)(&a3_s[pt * APAD + 128 + j * 32 + q * 8]) = p;
        }
    }
    __syncthreads();  // a3_s complete; MFMA loop below is barrier-free

    f32x4 acc[4][4];
    #pragma unroll
    for (int i = 0; i < 4; ++i)
        #pragma unroll
        for (int j = 0; j < 4; ++j)
            acc[i][j] = (f32x4){0.f, 0.f, 0.f, 0.f};

    const int w = t >> 6, lane = t & 63;
    const int llow = lane & 15, lhi = lane >> 4;

    for (int ks = 0; ks < 8; ++ks) {
        s16x8 bfrag[4];
        #pragma unroll
        for (int ci = 0; ci < 4; ++ci) {
            const int ct = w * 4 + ci;
            bfrag[ci] = *(const s16x8*)(wT3 + ((size_t)(ct * 8 + ks) * 64 + lane) * 8);
        }
        s16x8 afrag[4];
        #pragma unroll
        for (int rt = 0; rt < 4; ++rt)
            afrag[rt] = *(const s16x8*)(&a3_s[(rt * 16 + llow) * APAD + ks * 32 + lhi * 8]);
        #pragma unroll
        for (int ci = 0; ci < 4; ++ci)
            #pragma unroll
            for (int rt = 0; rt < 4; ++rt)
                acc[rt][ci] = __builtin_amdgcn_mfma_f32_16x16x32_bf16(
                    afrag[rt], bfrag[ci], acc[rt][ci], 0, 0, 0);
    }

    #pragma unroll
    for (int ci = 0; ci < 4; ++ci) {
        const int ct = w * 4 + ci;
        const int col = ct * 16 + llow;
        const float bias = b_fin[col];
        #pragma unroll
        for (int rt = 0; rt < 4; ++rt)
            #pragma unroll
            for (int r = 0; r < 4; ++r) {
                int row = base + rt * 16 + lhi * 4 + r;
                if (row < N) {
                    size_t o = (size_t)row * DIM + col;
                    out[o] = leaky(acc[rt][ci][r] + bias) + out[o];
                }
            }
    }
}

// ---------------------------------------------------------------------------
extern "C" void kernel_launch(void* const* d_in, const int* in_sizes, int n_in,
                              void* d_out, int out_size, void* d_ws, size_t ws_size,
                              hipStream_t stream) {
    const float* in    = (const float*)d_in[0];
    const float* geom  = (const float*)d_in[1];
    const int*   idx   = (const int*)d_in[2];
    const float* w_res = (const float*)d_in[3];
    const float* b_res = (const float*)d_in[4];
    const float* w_init= (const float*)d_in[5];
    const float* b_init= (const float*)d_in[6];
    const float* w_g1  = (const float*)d_in[7];
    const float* b_g1  = (const float*)d_in[8];
    const float* w_g2  = (const float*)d_in[9];
    const float* b_g2  = (const float*)d_in[10];
    const float* w_fin = (const float*)d_in[11];
    const float* b_fin = (const float*)d_in[12];
    float* out = (float*)d_out;

    const int N = in_sizes[0] / DIM;  // 50000

    // ws: a1 N*64 bf16 | a2 N*128 bf16 | wT1 320*256 bf16 | wT3 256*256 bf16
    char* ws = (char*)d_ws;
    u16* a1  = (u16*)ws;
    u16* a2  = a1 + (size_t)N * 64;
    u16* wT1 = a2 + (size_t)N * 128;
    u16* wT3 = wT1 + 320 * 256;

    k_prep<<<72, 256, 0, stream>>>(w_res, w_init, w_fin, wT1, wT3);
    k_gemm1<<<(N + 63) / 64, 256, 0, stream>>>(in, wT1, b_res, b_init, out, a1, N);
    k_lfa1<<<(N + 31) / 32, 256, 0, stream>>>(geom, idx, w_g1, b_g1, a1, a2, N);
    k_lfa2_fin<<<(N + 63) / 64, 256, 0, stream>>>(geom, idx, w_g2, b_g2, a2, wT3, b_fin, out, N);
}